// Round 3
// baseline (1064.426 us; speedup 1.0000x reference)
//
#include <hip/hip_runtime.h>
#include <math.h>

// ---- static problem constants ----
#define BZ 8
#define MAXL 5500
#define DD 64
// segment layout:
//   seg0: txt [0,225), img [225,2025)    (src s = L-225)
//   seg1: txt [2025,2250), img [2250,4050) (src s = L-2250+1800)
// attn squares: [0,2025)^2 and [2025,4050)^2

// output offsets (in floats), concatenated in reference return order
#define OFF_LOSS 0
#define OFF_TOK  8
#define OFF_TXT  (8 + BZ * MAXL * DD)          // 2,816,008
#define OFF_IMG  (OFF_TXT + BZ * MAXL)         // 2,860,008
#define OFF_POS  (OFF_IMG + BZ * MAXL)         // 2,904,008
#define OFF_ATTN (OFF_POS + BZ * MAXL * 3)     // 3,036,008  (%4 == 0 -> float4 ok)

#define ATTN_F4_PER_ROW (MAXL / 4)             // 1375
#define ATTN_F4_PER_B   (MAXL * (MAXL / 4))    // 7,562,500 float4 per batch copy
#define ATTN_F4_TOTAL   (BZ * ATTN_F4_PER_B)   // 60,500,000  (< 2^31)

// ------------------------------------------------------------------
// 968 MB broadcast attention mask.
// EXACTLY mirrors the runtime's fillBufferAligned access shape (which hits
// 6.25 TB/s on this buffer): one flat grid-stride loop, ONE 16 B store per
// iteration, single linear write stream per wave. Round-2's 8-way broadcast
// (65k concurrent 1 KB write streams) regressed -- DRAM page locality.
// Value from flat index: j = i4 % 7562500 (per-batch), r = j / 1375.
__global__ __launch_bounds__(256) void attn_kernel(float4* __restrict__ attn) {
    int stride = gridDim.x * 256;
    for (int i4 = blockIdx.x * 256 + threadIdx.x; i4 < ATTN_F4_TOTAL; i4 += stride) {
        int j = i4 % ATTN_F4_PER_B;                // magic-mul div
        int r = j / ATTN_F4_PER_ROW;               // magic-mul div by 1375
        int c = (j - r * ATTN_F4_PER_ROW) * 4;
        int lo, hi;
        if (r < 2025)      { lo = 0;    hi = 2025; }
        else if (r < 4050) { lo = 2025; hi = 4050; }
        else               { lo = 0;    hi = 0;    }
        float4 v;
        v.x = (c + 0 >= lo && c + 0 < hi) ? 1.f : 0.f;
        v.y = (c + 1 >= lo && c + 1 < hi) ? 1.f : 0.f;
        v.z = (c + 2 >= lo && c + 2 < hi) ? 1.f : 0.f;
        v.w = (c + 3 >= lo && c + 3 < hi) ? 1.f : 0.f;
        attn[i4] = v;
    }
}

// ------------------------------------------------------------------
// tokens gather + per-block loss partials. 4 tokens per 256-thread block.
__global__ __launch_bounds__(256) void token_kernel(
        const float* __restrict__ input, const float* __restrict__ noise,
        const float* __restrict__ alphas, float* __restrict__ out_tok,
        float* __restrict__ ws_partial) {
    int blk = blockIdx.x;                 // [0, BZ*1375)
    int b = blk / 1375;
    int Lbase = (blk % 1375) * 4;
    int t = threadIdx.x;
    int L = Lbase + (t >> 6);
    int d = t & 63;

    float tok = 0.f, contrib = 0.f;
    int s = -1;
    if (L >= 225 && L < 2025)       s = L - 225;
    else if (L >= 2250 && L < 4050) s = L - 2250 + 1800;
    if (s >= 0) {
        int g  = b * 3600 + s;
        int tf = g / 900;
        int rr = g - tf * 900;
        int hh = rr / 30;
        int ww = rr - hh * 30;
        int c = d & 15, q = (d >> 4) & 1, p = d >> 5;
        int iidx = ((tf * 16 + c) * 60 + (hh * 2 + p)) * 60 + (ww * 2 + q);
        tok = input[iidx];
        float nz  = noise[((size_t)b * MAXL + L) * DD + d];
        float a   = alphas[b];
        float sig = sqrtf(fmaxf(1.f - a * a, 0.f));
        float diff = tok * (a - 1.f) + nz * sig;
        contrib = diff * diff;
    }
    out_tok[((size_t)b * MAXL + L) * DD + d] = tok;

    // wave64 reduce + cross-wave LDS reduce -> one partial per block
    #pragma unroll
    for (int off = 32; off > 0; off >>= 1)
        contrib += __shfl_down(contrib, off, 64);
    __shared__ float lds[4];
    if ((t & 63) == 0) lds[t >> 6] = contrib;
    __syncthreads();
    if (t == 0) ws_partial[blk] = lds[0] + lds[1] + lds[2] + lds[3];
}

// ------------------------------------------------------------------
// txt/img masks + 3d position ids (tiny)
__global__ __launch_bounds__(256) void mask_kernel(float* __restrict__ out) {
    int L = blockIdx.x * 256 + threadIdx.x;
    if (L >= MAXL) return;
    float txt = ((L < 225) || (L >= 2025 && L < 2250)) ? 1.f : 0.f;
    int tloc = -1;
    if (L >= 225 && L < 2025)       tloc = L - 225;
    else if (L >= 2250 && L < 4050) tloc = L - 2250;   // pos ids reset per segment
    float img = (tloc >= 0) ? 1.f : 0.f;
    float pi = -1.f, pj = -1.f, pk = -1.f;
    if (tloc >= 0) {
        int fi = tloc / 900;
        int rr = tloc - fi * 900;
        pi = (float)fi;
        pj = (float)(rr / 30);
        pk = (float)(rr % 30);
    }
    float* txtp = out + OFF_TXT;
    float* imgp = out + OFF_IMG;
    float* posp = out + OFF_POS;
    #pragma unroll
    for (int b = 0; b < BZ; b++) {
        txtp[b * MAXL + L] = txt;
        imgp[b * MAXL + L] = img;
        posp[((size_t)b * MAXL + L) * 3 + 0] = pi;
        posp[((size_t)b * MAXL + L) * 3 + 1] = pj;
        posp[((size_t)b * MAXL + L) * 3 + 2] = pk;
    }
}

// ------------------------------------------------------------------
// final loss: one block per b sums its 1375 block partials
__global__ __launch_bounds__(256) void loss_kernel(
        const float* __restrict__ ws_partial, const float* __restrict__ alphas,
        float* __restrict__ out_loss) {
    int b = blockIdx.x;
    float s = 0.f;
    for (int i = threadIdx.x; i < 1375; i += 256)
        s += ws_partial[b * 1375 + i];
    #pragma unroll
    for (int off = 32; off > 0; off >>= 1)
        s += __shfl_down(s, off, 64);
    __shared__ float lds[4];
    if ((threadIdx.x & 63) == 0) lds[threadIdx.x >> 6] = s;
    __syncthreads();
    if (threadIdx.x == 0) {
        float tot = lds[0] + lds[1] + lds[2] + lds[3];
        float a = alphas[b];
        out_loss[b] = tot / ((1.f - a * a) * (float)(MAXL * DD));
    }
}

extern "C" void kernel_launch(void* const* d_in, const int* in_sizes, int n_in,
                              void* d_out, int out_size, void* d_ws, size_t ws_size,
                              hipStream_t stream) {
    const float* input  = (const float*)d_in[0];   // (1,32,16,60,60)
    const float* noise  = (const float*)d_in[1];   // (8,5500,64)
    const float* alphas = (const float*)d_in[2];   // (8,)
    float* out = (float*)d_out;
    float* ws  = (float*)d_ws;                     // 11,000 floats used

    attn_kernel <<<2048, 256, 0, stream>>>(reinterpret_cast<float4*>(out + OFF_ATTN));
    token_kernel<<<BZ * 1375, 256, 0, stream>>>(input, noise, alphas, out + OFF_TOK, ws);
    mask_kernel <<<(MAXL + 255) / 256, 256, 0, stream>>>(out);
    loss_kernel <<<BZ, 256, 0, stream>>>(ws, alphas, out + OFF_LOSS);
}

// Round 5
// 1020.955 us; speedup vs baseline: 1.0426x; 1.0426x over previous
//
#include <hip/hip_runtime.h>
#include <math.h>

// ---- static problem constants ----
#define BZ 8
#define MAXL 5500
#define DD 64
// segment layout:
//   seg0: txt [0,225), img [225,2025)    (src s = L-225)
//   seg1: txt [2025,2250), img [2250,4050) (src s = L-2250+1800)
// attn squares: [0,2025)^2 and [2025,4050)^2

// output offsets (in floats), concatenated in reference return order
#define OFF_LOSS 0
#define OFF_TOK  8
#define OFF_TXT  (8 + BZ * MAXL * DD)          // 2,816,008
#define OFF_IMG  (OFF_TXT + BZ * MAXL)         // 2,860,008
#define OFF_POS  (OFF_IMG + BZ * MAXL)         // 2,904,008
#define OFF_ATTN (OFF_POS + BZ * MAXL * 3)     // 3,036,008  (%4 == 0 -> float4 ok)

// native clang vector type: __builtin_nontemporal_store accepts this
// (it rejects HIP's struct-wrapped float4).
typedef float floatx4 __attribute__((ext_vector_type(4)));

// ------------------------------------------------------------------
// 968 MB broadcast attention mask: one block per (b,row) -- empirically the
// fastest structure (R0=996.7 vs grid-stride variants 1048/1064).
// NEW: non-temporal stores. Theory: plain write-back stores allocate+dirty
// +evict every L2 line (~2x L2 handling) capping the stream at ~2.6 TB/s;
// the runtime's fill kernel hits 6.2 TB/s on this same buffer. nt stores
// bypass L2 allocation and stream straight to DRAM.
__global__ __launch_bounds__(256) void attn_kernel(float* __restrict__ attn) {
    int br = blockIdx.x;                 // [0, BZ*MAXL)
    int r = br % MAXL;
    floatx4* row = reinterpret_cast<floatx4*>(attn + (size_t)br * MAXL);
    int lo, hi;
    if (r < 2025)      { lo = 0;    hi = 2025; }
    else if (r < 4050) { lo = 2025; hi = 4050; }
    else               { lo = 0;    hi = 0; }
    for (int c4 = threadIdx.x; c4 < MAXL / 4; c4 += 256) {
        int c = c4 * 4;
        floatx4 v;
        v.x = (c + 0 >= lo && c + 0 < hi) ? 1.f : 0.f;
        v.y = (c + 1 >= lo && c + 1 < hi) ? 1.f : 0.f;
        v.z = (c + 2 >= lo && c + 2 < hi) ? 1.f : 0.f;
        v.w = (c + 3 >= lo && c + 3 < hi) ? 1.f : 0.f;
        __builtin_nontemporal_store(v, &row[c4]);
    }
}

// ------------------------------------------------------------------
// tokens gather + per-block loss partials. 4 tokens per 256-thread block.
__global__ __launch_bounds__(256) void token_kernel(
        const float* __restrict__ input, const float* __restrict__ noise,
        const float* __restrict__ alphas, float* __restrict__ out_tok,
        float* __restrict__ ws_partial) {
    int blk = blockIdx.x;                 // [0, BZ*1375)
    int b = blk / 1375;
    int Lbase = (blk % 1375) * 4;
    int t = threadIdx.x;
    int L = Lbase + (t >> 6);
    int d = t & 63;

    float tok = 0.f, contrib = 0.f;
    int s = -1;
    if (L >= 225 && L < 2025)       s = L - 225;
    else if (L >= 2250 && L < 4050) s = L - 2250 + 1800;
    if (s >= 0) {
        int g  = b * 3600 + s;
        int tf = g / 900;
        int rr = g - tf * 900;
        int hh = rr / 30;
        int ww = rr - hh * 30;
        int c = d & 15, q = (d >> 4) & 1, p = d >> 5;
        int iidx = ((tf * 16 + c) * 60 + (hh * 2 + p)) * 60 + (ww * 2 + q);
        tok = input[iidx];
        float nz  = noise[((size_t)b * MAXL + L) * DD + d];
        float a   = alphas[b];
        float sig = sqrtf(fmaxf(1.f - a * a, 0.f));
        float diff = tok * (a - 1.f) + nz * sig;
        contrib = diff * diff;
    }
    out_tok[((size_t)b * MAXL + L) * DD + d] = tok;

    // wave64 reduce + cross-wave LDS reduce -> one partial per block
    #pragma unroll
    for (int off = 32; off > 0; off >>= 1)
        contrib += __shfl_down(contrib, off, 64);
    __shared__ float lds[4];
    if ((t & 63) == 0) lds[t >> 6] = contrib;
    __syncthreads();
    if (t == 0) ws_partial[blk] = lds[0] + lds[1] + lds[2] + lds[3];
}

// ------------------------------------------------------------------
// txt/img masks + 3d position ids (tiny)
__global__ __launch_bounds__(256) void mask_kernel(float* __restrict__ out) {
    int L = blockIdx.x * 256 + threadIdx.x;
    if (L >= MAXL) return;
    float txt = ((L < 225) || (L >= 2025 && L < 2250)) ? 1.f : 0.f;
    int tloc = -1;
    if (L >= 225 && L < 2025)       tloc = L - 225;
    else if (L >= 2250 && L < 4050) tloc = L - 2250;   // pos ids reset per segment
    float img = (tloc >= 0) ? 1.f : 0.f;
    float pi = -1.f, pj = -1.f, pk = -1.f;
    if (tloc >= 0) {
        int fi = tloc / 900;
        int rr = tloc - fi * 900;
        pi = (float)fi;
        pj = (float)(rr / 30);
        pk = (float)(rr % 30);
    }
    float* txtp = out + OFF_TXT;
    float* imgp = out + OFF_IMG;
    float* posp = out + OFF_POS;
    #pragma unroll
    for (int b = 0; b < BZ; b++) {
        txtp[b * MAXL + L] = txt;
        imgp[b * MAXL + L] = img;
        posp[((size_t)b * MAXL + L) * 3 + 0] = pi;
        posp[((size_t)b * MAXL + L) * 3 + 1] = pj;
        posp[((size_t)b * MAXL + L) * 3 + 2] = pk;
    }
}

// ------------------------------------------------------------------
// final loss: one block per b sums its 1375 block partials
__global__ __launch_bounds__(256) void loss_kernel(
        const float* __restrict__ ws_partial, const float* __restrict__ alphas,
        float* __restrict__ out_loss) {
    int b = blockIdx.x;
    float s = 0.f;
    for (int i = threadIdx.x; i < 1375; i += 256)
        s += ws_partial[b * 1375 + i];
    #pragma unroll
    for (int off = 32; off > 0; off >>= 1)
        s += __shfl_down(s, off, 64);
    __shared__ float lds[4];
    if ((threadIdx.x & 63) == 0) lds[threadIdx.x >> 6] = s;
    __syncthreads();
    if (threadIdx.x == 0) {
        float tot = lds[0] + lds[1] + lds[2] + lds[3];
        float a = alphas[b];
        out_loss[b] = tot / ((1.f - a * a) * (float)(MAXL * DD));
    }
}

extern "C" void kernel_launch(void* const* d_in, const int* in_sizes, int n_in,
                              void* d_out, int out_size, void* d_ws, size_t ws_size,
                              hipStream_t stream) {
    const float* input  = (const float*)d_in[0];   // (1,32,16,60,60)
    const float* noise  = (const float*)d_in[1];   // (8,5500,64)
    const float* alphas = (const float*)d_in[2];   // (8,)
    float* out = (float*)d_out;
    float* ws  = (float*)d_ws;                     // 11,000 floats used

    attn_kernel <<<BZ * MAXL, 256, 0, stream>>>(out + OFF_ATTN);
    token_kernel<<<BZ * 1375, 256, 0, stream>>>(input, noise, alphas, out + OFF_TOK, ws);
    mask_kernel <<<(MAXL + 255) / 256, 256, 0, stream>>>(out);
    loss_kernel <<<BZ, 256, 0, stream>>>(ws, alphas, out + OFF_LOSS);
}

// Round 6
// 994.728 us; speedup vs baseline: 1.0701x; 1.0264x over previous
//
#include <hip/hip_runtime.h>
#include <math.h>

// ---- static problem constants ----
#define BZ 8
#define MAXL 5500
#define DD 64
// segment layout:
//   seg0: txt [0,225), img [225,2025)    (src s = L-225)
//   seg1: txt [2025,2250), img [2250,4050) (src s = L-2250+1800)
// attn squares: [0,2025)^2 and [2025,4050)^2

// output offsets (in floats), concatenated in reference return order
#define OFF_LOSS 0
#define OFF_TOK  8
#define OFF_TXT  (8 + BZ * MAXL * DD)          // 2,816,008
#define OFF_IMG  (OFF_TXT + BZ * MAXL)         // 2,860,008
#define OFF_POS  (OFF_IMG + BZ * MAXL)         // 2,904,008
#define OFF_ATTN (OFF_POS + BZ * MAXL * 3)     // 3,036,008  (%4 == 0 -> float4 ok)

// ------------------------------------------------------------------
// 968 MB broadcast attention mask: one block per (b,row), float4 stores.
// Empirically the best of four structurally different write patterns
// (996.7 vs 1048 / 1064 / 1021 µs). The iteration is bound by the
// sustained pure-write DRAM stream (harness 3.92 GB poison + our 0.98 GB
// at ~4.9 TB/s aggregate); pattern/cache-policy changes only subtract.
__global__ __launch_bounds__(256) void attn_kernel(float* __restrict__ attn) {
    int br = blockIdx.x;                 // [0, BZ*MAXL)
    int r = br % MAXL;
    float* row = attn + (size_t)br * MAXL;
    int lo, hi;
    if (r < 2025)      { lo = 0;    hi = 2025; }
    else if (r < 4050) { lo = 2025; hi = 4050; }
    else               { lo = 0;    hi = 0; }
    for (int c4 = threadIdx.x; c4 < MAXL / 4; c4 += 256) {
        int c = c4 * 4;
        float4 v;
        v.x = (c + 0 >= lo && c + 0 < hi) ? 1.f : 0.f;
        v.y = (c + 1 >= lo && c + 1 < hi) ? 1.f : 0.f;
        v.z = (c + 2 >= lo && c + 2 < hi) ? 1.f : 0.f;
        v.w = (c + 3 >= lo && c + 3 < hi) ? 1.f : 0.f;
        reinterpret_cast<float4*>(row)[c4] = v;
    }
}

// ------------------------------------------------------------------
// tokens gather + per-block loss partials. 4 tokens per 256-thread block.
__global__ __launch_bounds__(256) void token_kernel(
        const float* __restrict__ input, const float* __restrict__ noise,
        const float* __restrict__ alphas, float* __restrict__ out_tok,
        float* __restrict__ ws_partial) {
    int blk = blockIdx.x;                 // [0, BZ*1375)
    int b = blk / 1375;
    int Lbase = (blk % 1375) * 4;
    int t = threadIdx.x;
    int L = Lbase + (t >> 6);
    int d = t & 63;

    float tok = 0.f, contrib = 0.f;
    int s = -1;
    if (L >= 225 && L < 2025)       s = L - 225;
    else if (L >= 2250 && L < 4050) s = L - 2250 + 1800;
    if (s >= 0) {
        int g  = b * 3600 + s;
        int tf = g / 900;
        int rr = g - tf * 900;
        int hh = rr / 30;
        int ww = rr - hh * 30;
        int c = d & 15, q = (d >> 4) & 1, p = d >> 5;
        int iidx = ((tf * 16 + c) * 60 + (hh * 2 + p)) * 60 + (ww * 2 + q);
        tok = input[iidx];
        float nz  = noise[((size_t)b * MAXL + L) * DD + d];
        float a   = alphas[b];
        float sig = sqrtf(fmaxf(1.f - a * a, 0.f));
        float diff = tok * (a - 1.f) + nz * sig;
        contrib = diff * diff;
    }
    out_tok[((size_t)b * MAXL + L) * DD + d] = tok;

    // wave64 reduce + cross-wave LDS reduce -> one partial per block
    #pragma unroll
    for (int off = 32; off > 0; off >>= 1)
        contrib += __shfl_down(contrib, off, 64);
    __shared__ float lds[4];
    if ((t & 63) == 0) lds[t >> 6] = contrib;
    __syncthreads();
    if (t == 0) ws_partial[blk] = lds[0] + lds[1] + lds[2] + lds[3];
}

// ------------------------------------------------------------------
// txt/img masks + 3d position ids (tiny)
__global__ __launch_bounds__(256) void mask_kernel(float* __restrict__ out) {
    int L = blockIdx.x * 256 + threadIdx.x;
    if (L >= MAXL) return;
    float txt = ((L < 225) || (L >= 2025 && L < 2250)) ? 1.f : 0.f;
    int tloc = -1;
    if (L >= 225 && L < 2025)       tloc = L - 225;
    else if (L >= 2250 && L < 4050) tloc = L - 2250;   // pos ids reset per segment
    float img = (tloc >= 0) ? 1.f : 0.f;
    float pi = -1.f, pj = -1.f, pk = -1.f;
    if (tloc >= 0) {
        int fi = tloc / 900;
        int rr = tloc - fi * 900;
        pi = (float)fi;
        pj = (float)(rr / 30);
        pk = (float)(rr % 30);
    }
    float* txtp = out + OFF_TXT;
    float* imgp = out + OFF_IMG;
    float* posp = out + OFF_POS;
    #pragma unroll
    for (int b = 0; b < BZ; b++) {
        txtp[b * MAXL + L] = txt;
        imgp[b * MAXL + L] = img;
        posp[((size_t)b * MAXL + L) * 3 + 0] = pi;
        posp[((size_t)b * MAXL + L) * 3 + 1] = pj;
        posp[((size_t)b * MAXL + L) * 3 + 2] = pk;
    }
}

// ------------------------------------------------------------------
// final loss: one block per b sums its 1375 block partials
__global__ __launch_bounds__(256) void loss_kernel(
        const float* __restrict__ ws_partial, const float* __restrict__ alphas,
        float* __restrict__ out_loss) {
    int b = blockIdx.x;
    float s = 0.f;
    for (int i = threadIdx.x; i < 1375; i += 256)
        s += ws_partial[b * 1375 + i];
    #pragma unroll
    for (int off = 32; off > 0; off >>= 1)
        s += __shfl_down(s, off, 64);
    __shared__ float lds[4];
    if ((threadIdx.x & 63) == 0) lds[threadIdx.x >> 6] = s;
    __syncthreads();
    if (threadIdx.x == 0) {
        float tot = lds[0] + lds[1] + lds[2] + lds[3];
        float a = alphas[b];
        out_loss[b] = tot / ((1.f - a * a) * (float)(MAXL * DD));
    }
}

extern "C" void kernel_launch(void* const* d_in, const int* in_sizes, int n_in,
                              void* d_out, int out_size, void* d_ws, size_t ws_size,
                              hipStream_t stream) {
    const float* input  = (const float*)d_in[0];   // (1,32,16,60,60)
    const float* noise  = (const float*)d_in[1];   // (8,5500,64)
    const float* alphas = (const float*)d_in[2];   // (8,)
    float* out = (float*)d_out;
    float* ws  = (float*)d_ws;                     // 11,000 floats used

    attn_kernel <<<BZ * MAXL, 256, 0, stream>>>(out + OFF_ATTN);
    token_kernel<<<BZ * 1375, 256, 0, stream>>>(input, noise, alphas, out + OFF_TOK, ws);
    mask_kernel <<<(MAXL + 255) / 256, 256, 0, stream>>>(out);
    loss_kernel <<<BZ, 256, 0, stream>>>(ws, alphas, out + OFF_LOSS);
}